// Round 7
// baseline (129.457 us; speedup 1.0000x reference)
//
#include <hip/hip_runtime.h>
#include <hip/hip_bf16.h>

#define B_   2
#define S_   2048
#define H_   16
#define D_   64
#define DIM_ 1024
#define QKV_SZ (32 * 2048 * 64)

typedef __attribute__((ext_vector_type(8))) short bf16x8;
typedef __attribute__((ext_vector_type(4))) float f32x4;
typedef unsigned short u16;
typedef unsigned int u32;

static __device__ __forceinline__ u16 f2bf(float f) {      // RNE
    union { float f; unsigned u; } v; v.f = f;
    unsigned u = v.u;
    unsigned r = (u + 0x7fffu + ((u >> 16) & 1u)) >> 16;
    return (u16)r;
}
static __device__ __forceinline__ float exp2_fast(float x) {
    float r; asm("v_exp_f32 %0, %1" : "=v"(r) : "v"(x)); return r;
}
static __device__ __forceinline__ u32 cvtpk_bf16(float lo, float hi) {
    u32 r; asm("v_cvt_pk_bf16_f32 %0, %1, %2" : "=v"(r) : "v"(lo), "v"(hi)); return r;
}
static __device__ __forceinline__ void gload_lds16(const u16* g, u16* l) {
    __builtin_amdgcn_global_load_lds(
        (const __attribute__((address_space(1))) void*)g,
        (__attribute__((address_space(3))) void*)l, 16, 0, 0);
}

// ---------------------------------------------------------------- LayerNorm
__global__ __launch_bounds__(256) void ln_kernel(
    const float* __restrict__ x, const float* __restrict__ g,
    const float* __restrict__ b, u16* __restrict__ hb)
{
    int row = blockIdx.x;
    int t = threadIdx.x;
    const float4 v = ((const float4*)(x + row * DIM_))[t];
    float s  = v.x + v.y + v.z + v.w;
    float ss = v.x*v.x + v.y*v.y + v.z*v.z + v.w*v.w;
#pragma unroll
    for (int m = 1; m < 64; m <<= 1) { s += __shfl_xor(s, m); ss += __shfl_xor(ss, m); }
    __shared__ float rs[4], rss[4];
    int wid = t >> 6, lane = t & 63;
    if (lane == 0) { rs[wid] = s; rss[wid] = ss; }
    __syncthreads();
    s  = rs[0] + rs[1] + rs[2] + rs[3];
    ss = rss[0] + rss[1] + rss[2] + rss[3];
    float mu   = s * (1.0f / DIM_);
    float var  = ss * (1.0f / DIM_) - mu * mu;
    float rstd = rsqrtf(var + 1e-6f);
    const float4 gv = ((const float4*)g)[t];
    const float4 bv = ((const float4*)b)[t];
    ushort4 ov;
    ov.x = f2bf((v.x - mu) * rstd * gv.x + bv.x);
    ov.y = f2bf((v.y - mu) * rstd * gv.y + bv.y);
    ov.z = f2bf((v.z - mu) * rstd * gv.z + bv.z);
    ov.w = f2bf((v.w - mu) * rstd * gv.w + bv.w);
    ((ushort4*)(hb + row * DIM_))[t] = ov;
}

// ---------------------------------------------------------------- fp32 -> bf16 transpose
__global__ __launch_bounds__(256) void transpose_f32_bf16(
    const float* __restrict__ src, u16* __restrict__ dst, int R, int C)
{
    __shared__ u16 T[64][65];
    int c0 = blockIdx.x * 64, r0 = blockIdx.y * 64;
    int t = threadIdx.x;
    int rl = t >> 4, cl = (t & 15) * 4;
#pragma unroll
    for (int p = 0; p < 4; p++) {
        float4 v = *(const float4*)(src + (size_t)(r0 + rl + p * 16) * C + c0 + cl);
        T[cl + 0][rl + p * 16] = f2bf(v.x);
        T[cl + 1][rl + p * 16] = f2bf(v.y);
        T[cl + 2][rl + p * 16] = f2bf(v.z);
        T[cl + 3][rl + p * 16] = f2bf(v.w);
    }
    __syncthreads();
#pragma unroll
    for (int p = 0; p < 4; p++) {
        ushort4 o;
        o.x = T[rl + p * 16][cl + 0];
        o.y = T[rl + p * 16][cl + 1];
        o.z = T[rl + p * 16][cl + 2];
        o.w = T[rl + p * 16][cl + 3];
        *(ushort4*)(dst + (size_t)(c0 + rl + p * 16) * R + r0 + cl) = o;
    }
}

// ---------------------------------------------------------------- QKV GEMM 128x128
// Double-buffered LDS pipeline (stage t+1 issued before compute of t; ONE
// barrier per K-step whose implicit vmcnt/lgkm drain provides all ordering).
// Epilogue: Q pre-scaled by 0.125*log2(e), K [bh][s][64], V transposed [bh][d][s].
__global__ __launch_bounds__(256) void qkv_gemm128(
    const u16* __restrict__ A, const u16* __restrict__ Bw,
    const float* __restrict__ bias, u16* __restrict__ qkv)
{
    __shared__ __align__(16) u16 As[2][128 * 32];
    __shared__ __align__(16) u16 Bs[2][128 * 32];
    int t = threadIdx.x;
    int bn = blockIdx.x * 128, bm = blockIdx.y * 128;
    int wid = t >> 6, lane = t & 63;
    int wm = wid >> 1, wn = wid & 1;
    int l15 = lane & 15, l4 = lane >> 4;

    f32x4 zero = {0.f, 0.f, 0.f, 0.f};
    f32x4 acc[4][4];
#pragma unroll
    for (int i = 0; i < 4; i++)
#pragma unroll
        for (int j = 0; j < 4; j++) acc[i][j] = zero;

    const u16* aSrc = A  + (size_t)(bm + wid * 32 + (lane >> 2)) * 1024 + (lane & 3) * 8;
    const u16* bSrc = Bw + (size_t)(bn + wid * 32 + (lane >> 2)) * 1024 + (lane & 3) * 8;

#define STAGE_G(bufsel, kk) do { \
        char* Ad = (char*)As + (bufsel) * 8192 + wid * 2048; \
        char* Bd = (char*)Bs + (bufsel) * 8192 + wid * 2048; \
        gload_lds16(aSrc + (kk),             (u16*)Ad); \
        gload_lds16(aSrc + (kk) + 16 * 1024, (u16*)(Ad + 1024)); \
        gload_lds16(bSrc + (kk),             (u16*)Bd); \
        gload_lds16(bSrc + (kk) + 16 * 1024, (u16*)(Bd + 1024)); \
    } while (0)

    STAGE_G(0, 0);
    __syncthreads();
    int cur = 0;
    for (int kt = 0; kt < 32; ++kt) {
        if (kt < 31) STAGE_G(cur ^ 1, (kt + 1) * 32);
        const char* Ab = (const char*)As + cur * 8192;
        const char* Bb = (const char*)Bs + cur * 8192;
        bf16x8 af[4], bf[4];
#pragma unroll
        for (int mi = 0; mi < 4; mi++)
            af[mi] = *(const bf16x8*)(Ab + (wm * 64 + mi * 16 + l15) * 64 + l4 * 16);
#pragma unroll
        for (int ni = 0; ni < 4; ni++)
            bf[ni] = *(const bf16x8*)(Bb + (wn * 64 + ni * 16 + l15) * 64 + l4 * 16);
        __builtin_amdgcn_s_setprio(1);
#pragma unroll
        for (int mi = 0; mi < 4; mi++)
#pragma unroll
            for (int ni = 0; ni < 4; ni++)
                acc[mi][ni] = __builtin_amdgcn_mfma_f32_16x16x32_bf16(af[mi], bf[ni], acc[mi][ni], 0, 0, 0);
        __builtin_amdgcn_s_setprio(0);
        __syncthreads();
        cur ^= 1;
    }
#pragma unroll
    for (int mi = 0; mi < 4; mi++)
#pragma unroll
        for (int ni = 0; ni < 4; ni++) {
            int col = bn + wn * 64 + ni * 16 + l15;
            int which = col >> 10, f = col & 1023;
            int hh = f >> 6, d = f & 63;
            float bs = bias[col];
            if (which == 2) {
                int s_base = bm + wm * 64 + mi * 16 + l4 * 4;
                int bb = s_base >> 11, s = s_base & 2047;
                ushort4 pk;
                pk.x = f2bf(acc[mi][ni][0] + bs);
                pk.y = f2bf(acc[mi][ni][1] + bs);
                pk.z = f2bf(acc[mi][ni][2] + bs);
                pk.w = f2bf(acc[mi][ni][3] + bs);
                *(ushort4*)(qkv + (size_t)2 * QKV_SZ +
                            ((size_t)(bb * 16 + hh) * 64 + d) * 2048 + s) = pk;
            } else {
                float scl = (which == 0) ? 0.18033688011112042f : 1.0f; // 0.125*log2(e)
#pragma unroll
                for (int r = 0; r < 4; r++) {
                    int row = bm + wm * 64 + mi * 16 + l4 * 4 + r;
                    int bb = row >> 11, s = row & 2047;
                    qkv[(size_t)which * QKV_SZ + ((size_t)(bb * 16 + hh) * 2048 + s) * 64 + d] =
                        f2bf((acc[mi][ni][r] + bs) * scl);
                }
            }
        }
}

// ---------------------------------------------------------------- Out GEMM 128x128 + residual
// Same double-buffered pipeline.
__global__ __launch_bounds__(256) void out_gemm128(
    const u16* __restrict__ A, const u16* __restrict__ Bw,
    const float* __restrict__ bias, const float* __restrict__ xres,
    float* __restrict__ out)
{
    __shared__ __align__(16) u16 As[2][128 * 32];
    __shared__ __align__(16) u16 Bs[2][128 * 32];
    int t = threadIdx.x;
    int bn = blockIdx.x * 128, bm = blockIdx.y * 128;
    int wid = t >> 6, lane = t & 63;
    int wm = wid >> 1, wn = wid & 1;
    int l15 = lane & 15, l4 = lane >> 4;

    f32x4 zero = {0.f, 0.f, 0.f, 0.f};
    f32x4 acc[4][4];
#pragma unroll
    for (int i = 0; i < 4; i++)
#pragma unroll
        for (int j = 0; j < 4; j++) acc[i][j] = zero;

    const u16* aSrc = A  + (size_t)(bm + wid * 32 + (lane >> 2)) * 1024 + (lane & 3) * 8;
    const u16* bSrc = Bw + (size_t)(bn + wid * 32 + (lane >> 2)) * 1024 + (lane & 3) * 8;

    STAGE_G(0, 0);
    __syncthreads();
    int cur = 0;
    for (int kt = 0; kt < 32; ++kt) {
        if (kt < 31) STAGE_G(cur ^ 1, (kt + 1) * 32);
        const char* Ab = (const char*)As + cur * 8192;
        const char* Bb = (const char*)Bs + cur * 8192;
        bf16x8 af[4], bf[4];
#pragma unroll
        for (int mi = 0; mi < 4; mi++)
            af[mi] = *(const bf16x8*)(Ab + (wm * 64 + mi * 16 + l15) * 64 + l4 * 16);
#pragma unroll
        for (int ni = 0; ni < 4; ni++)
            bf[ni] = *(const bf16x8*)(Bb + (wn * 64 + ni * 16 + l15) * 64 + l4 * 16);
        __builtin_amdgcn_s_setprio(1);
#pragma unroll
        for (int mi = 0; mi < 4; mi++)
#pragma unroll
            for (int ni = 0; ni < 4; ni++)
                acc[mi][ni] = __builtin_amdgcn_mfma_f32_16x16x32_bf16(af[mi], bf[ni], acc[mi][ni], 0, 0, 0);
        __builtin_amdgcn_s_setprio(0);
        __syncthreads();
        cur ^= 1;
    }
#pragma unroll
    for (int mi = 0; mi < 4; mi++)
#pragma unroll
        for (int ni = 0; ni < 4; ni++) {
            int col = bn + wn * 64 + ni * 16 + l15;
            float bs = bias[col];
#pragma unroll
            for (int r = 0; r < 4; r++) {
                int row = bm + wm * 64 + mi * 16 + l4 * 4 + r;
                out[(size_t)row * 1024 + col] = xres[(size_t)row * 1024 + col] + acc[mi][ni][r] + bs;
            }
        }
}

// ---------------------------------------------------------------- Flash attention
// (unchanged from round 6 — swapped QK^T, deferred max, per-lane partial sums,
//  packed P writes, conflict-free swizzles, clamped register prefetch)
__global__ __launch_bounds__(256) void attn_kernel(
    const u16* __restrict__ qbuf, const u16* __restrict__ kbuf,
    const u16* __restrict__ vbuf, u16* __restrict__ ctx)
{
    __shared__ __align__(16) char Ks[64 * 128];
    __shared__ __align__(16) char Vt[64 * 128];
    __shared__ __align__(16) char Pb[4 * 16 * 128];

    int t = threadIdx.x, wid = t >> 6, lane = t & 63;
    int l15 = lane & 15, l4 = lane >> 4;
    int idx = blockIdx.x;
    int qt = 31 - (idx >> 5);          // longest blocks first
    int bh = idx & 31;
    int q0 = qt * 64;
    int sr = t >> 3, g = t & 7;
    int bb = bh >> 4, hh = bh & 15;
    f32x4 zero = {0.f, 0.f, 0.f, 0.f};

    const u16* Q = qbuf + (size_t)(bh * 2048 + q0 + wid * 16) * 64;
    bf16x8 aq0 = *(const bf16x8*)(Q + l15 * 64 + 8 * l4);
    bf16x8 aq1 = *(const bf16x8*)(Q + l15 * 64 + 32 + 8 * l4);

    f32x4 o[4];
#pragma unroll
    for (int f = 0; f < 4; f++) o[f] = zero;
    float m_run = -1e30f;
    float l_run = 0.f;

    int kswz = (16 * g) ^ ((sr & 7) << 4);
    char* Pw = Pb + wid * 2048;
    int prow = l15 * 128;
    int pkey = (l15 & 7) << 4;
    int qloc = wid * 16 + l15;

    const u16* Kbase = kbuf + (size_t)bh * 2048 * 64;      // [s][64]
    const u16* Vbase = vbuf + (size_t)bh * 64 * 2048;      // [d][s]

    bf16x8 ck0 = *(const bf16x8*)(Kbase + (size_t)sr * 64 + g * 8);
    bf16x8 ck1 = *(const bf16x8*)(Kbase + (size_t)(sr + 32) * 64 + g * 8);
    bf16x8 cv0 = *(const bf16x8*)(Vbase + (size_t)sr * 2048 + g * 8);
    bf16x8 cv1 = *(const bf16x8*)(Vbase + (size_t)(sr + 32) * 2048 + g * 8);

    for (int kt = 0; kt <= qt; ++kt) {
        *(bf16x8*)(Ks + sr * 128 + kswz) = ck0;
        *(bf16x8*)(Ks + (sr + 32) * 128 + kswz) = ck1;
        *(bf16x8*)(Vt + sr * 128 + kswz) = cv0;
        *(bf16x8*)(Vt + (sr + 32) * 128 + kswz) = cv1;
        {
            int nkt = (kt < qt) ? kt + 1 : qt;   // clamped -> always initialized
            const u16* Kn = Kbase + (size_t)nkt * 64 * 64;
            const u16* Vn = Vbase + (size_t)nkt * 64;
            bf16x8 a = *(const bf16x8*)(Kn + (size_t)sr * 64 + g * 8);
            bf16x8 b = *(const bf16x8*)(Kn + (size_t)(sr + 32) * 64 + g * 8);
            bf16x8 c = *(const bf16x8*)(Vn + (size_t)sr * 2048 + g * 8);
            bf16x8 d = *(const bf16x8*)(Vn + (size_t)(sr + 32) * 2048 + g * 8);
            __syncthreads();

            // ---- scores (swapped): sc[nf][r] = S[ka=nf*16+4*l4+r][q=l15]
            f32x4 sc[4];
            __builtin_amdgcn_s_setprio(1);
#pragma unroll
            for (int nf = 0; nf < 4; ++nf) {
                int krow = nf * 16 + l15;
                int kkey = (krow & 7) << 4;
                bf16x8 kb0 = *(const bf16x8*)(Ks + krow * 128 + ((16 * l4) ^ kkey));
                bf16x8 kb1 = *(const bf16x8*)(Ks + krow * 128 + ((64 + 16 * l4) ^ kkey));
                f32x4 z = zero;
                z = __builtin_amdgcn_mfma_f32_16x16x32_bf16(kb0, aq0, z, 0, 0, 0);
                z = __builtin_amdgcn_mfma_f32_16x16x32_bf16(kb1, aq1, z, 0, 0, 0);
                sc[nf] = z;
            }
            __builtin_amdgcn_s_setprio(0);

            if (kt == qt) {
#pragma unroll
                for (int nf = 0; nf < 4; nf++)
#pragma unroll
                    for (int r = 0; r < 4; r++) {
                        int ka = nf * 16 + 4 * l4 + r;
                        if (ka > qloc) sc[nf][r] = -1e30f;
                    }
            }
            // ---- local max + deferred global max
            float lmax = sc[0][0];
#pragma unroll
            for (int nf = 0; nf < 4; nf++)
#pragma unroll
                for (int r = 0; r < 4; r++) lmax = fmaxf(lmax, sc[nf][r]);
            if (__any(lmax > m_run + 10.f)) {
                float m0 = lmax;
                m0 = fmaxf(m0, __shfl_xor(m0, 16));
                m0 = fmaxf(m0, __shfl_xor(m0, 32));
                float mn = fmaxf(m_run, m0);
                float al = exp2_fast(m_run - mn);
                l_run *= al;
                m_run = mn;
                float a0 = __shfl(al, 4 * l4 + 0);
                float a1 = __shfl(al, 4 * l4 + 1);
                float a2 = __shfl(al, 4 * l4 + 2);
                float a3 = __shfl(al, 4 * l4 + 3);
#pragma unroll
                for (int f = 0; f < 4; f++) {
                    o[f][0] *= a0; o[f][1] *= a1; o[f][2] *= a2; o[f][3] *= a3;
                }
            }
            // ---- exp2 + per-lane partial sum
            float psum = 0.f;
#pragma unroll
            for (int nf = 0; nf < 4; nf++)
#pragma unroll
                for (int r = 0; r < 4; r++) {
                    float pv = exp2_fast(sc[nf][r] - m_run);
                    sc[nf][r] = pv; psum += pv;
                }
            l_run += psum;
            // ---- P pack + write (k-consecutive quad per lane)
#pragma unroll
            for (int nf = 0; nf < 4; nf++) {
                uint2 w;
                w.x = cvtpk_bf16(sc[nf][0], sc[nf][1]);
                w.y = cvtpk_bf16(sc[nf][2], sc[nf][3]);
                *(uint2*)(Pw + prow + ((nf * 32 + l4 * 8) ^ pkey)) = w;
            }
            // ---- P @ V
            __builtin_amdgcn_s_setprio(1);
#pragma unroll
            for (int kk = 0; kk < 2; kk++) {
                bf16x8 pa = *(const bf16x8*)(Pw + prow + ((64 * kk + 16 * l4) ^ pkey));
#pragma unroll
                for (int f = 0; f < 4; f++) {
                    int vrow = f * 16 + l15;
                    int vkey = (vrow & 7) << 4;
                    bf16x8 vb = *(const bf16x8*)(Vt + vrow * 128 + ((64 * kk + 16 * l4) ^ vkey));
                    o[f] = __builtin_amdgcn_mfma_f32_16x16x32_bf16(pa, vb, o[f], 0, 0, 0);
                }
            }
            __builtin_amdgcn_s_setprio(0);
            __syncthreads();
            ck0 = a; ck1 = b; cv0 = c; cv1 = d;
        }
    }
    // ---- final row-sum reduce
    l_run += __shfl_xor(l_run, 16);
    l_run += __shfl_xor(l_run, 32);
#pragma unroll
    for (int r = 0; r < 4; r++) {
        float lr = __shfl(l_run, 4 * l4 + r);
        float inv = 1.f / lr;
        int qa = q0 + wid * 16 + l4 * 4 + r;
        u16* dst = ctx + (size_t)(bb * 2048 + qa) * 1024 + hh * 64;
#pragma unroll
        for (int f = 0; f < 4; f++) dst[f * 16 + l15] = f2bf(o[f][r] * inv);
    }
}

// ----------------------------------------------------------------
extern "C" void kernel_launch(void* const* d_in, const int* in_sizes, int n_in,
                              void* d_out, int out_size, void* d_ws, size_t ws_size,
                              hipStream_t stream)
{
    const float* x    = (const float*)d_in[0];
    const float* ln_g = (const float*)d_in[1];
    const float* ln_b = (const float*)d_in[2];
    const float* wqkv = (const float*)d_in[3];
    const float* bqkv = (const float*)d_in[4];
    const float* wo   = (const float*)d_in[5];
    const float* bo   = (const float*)d_in[6];
    float* out = (float*)d_out;

    char* ws = (char*)d_ws;
    u16* hbuf  = (u16*)ws;                          // 8 MB   (LN out; later woT reuses front)
    u16* qkvb  = (u16*)(ws + 8388608);              // 24 MB  q/k head-major, v transposed
    u16* ctxb  = (u16*)(ws + 33554432);             // 8 MB   (wqkvT first, then ctx)
    u16* wqkvT = ctxb;                              // 6.29 MB (dead before attn writes ctx)
    u16* woT   = hbuf;                              // 2 MB   (hbuf dead after qkv_gemm)

    transpose_f32_bf16<<<dim3(48, 16), 256, 0, stream>>>(wqkv, wqkvT, 1024, 3072);
    ln_kernel<<<4096, 256, 0, stream>>>(x, ln_g, ln_b, hbuf);
    qkv_gemm128<<<dim3(24, 32), 256, 0, stream>>>(hbuf, wqkvT, bqkv, qkvb);
    transpose_f32_bf16<<<dim3(16, 16), 256, 0, stream>>>(wo, woT, 1024, 1024);
    attn_kernel<<<1024, 256, 0, stream>>>(
        qkvb, qkvb + QKV_SZ, qkvb + 2 * QKV_SZ, ctxb);
    out_gemm128<<<dim3(8, 32), 256, 0, stream>>>(ctxb, woT, bo, x, out);
}

// Round 8
// 118.690 us; speedup vs baseline: 1.0907x; 1.0907x over previous
//
#include <hip/hip_runtime.h>
#include <hip/hip_bf16.h>

#define B_   2
#define S_   2048
#define H_   16
#define D_   64
#define DIM_ 1024
#define QKV_SZ (32 * 2048 * 64)

typedef __attribute__((ext_vector_type(8))) short bf16x8;
typedef __attribute__((ext_vector_type(4))) float f32x4;
typedef unsigned short u16;
typedef unsigned int u32;

static __device__ __forceinline__ u16 f2bf(float f) {      // RNE
    union { float f; unsigned u; } v; v.f = f;
    unsigned u = v.u;
    unsigned r = (u + 0x7fffu + ((u >> 16) & 1u)) >> 16;
    return (u16)r;
}
static __device__ __forceinline__ float exp2_fast(float x) {
    float r; asm("v_exp_f32 %0, %1" : "=v"(r) : "v"(x)); return r;
}
static __device__ __forceinline__ u32 cvtpk_bf16(float lo, float hi) {
    u32 r; asm("v_cvt_pk_bf16_f32 %0, %1, %2" : "=v"(r) : "v"(lo), "v"(hi)); return r;
}
static __device__ __forceinline__ void gload_lds16(const u16* g, u16* l) {
    __builtin_amdgcn_global_load_lds(
        (const __attribute__((address_space(1))) void*)g,
        (__attribute__((address_space(3))) void*)l, 16, 0, 0);
}

// ---------------------------------------------------------------- prep: LN + wqkv transpose (merged)
__global__ __launch_bounds__(256) void prep_kernel(
    const float* __restrict__ x, const float* __restrict__ g,
    const float* __restrict__ b, u16* __restrict__ hb,
    const float* __restrict__ wqkv, u16* __restrict__ wqkvT)
{
    __shared__ u16 T[64][65];
    __shared__ float rs[4], rss[4];
    int bid = blockIdx.x;
    int t = threadIdx.x;
    if (bid < 4096) {
        // ---------------- LayerNorm row
        int row = bid;
        const float4 v = ((const float4*)(x + row * DIM_))[t];
        float s  = v.x + v.y + v.z + v.w;
        float ss = v.x*v.x + v.y*v.y + v.z*v.z + v.w*v.w;
#pragma unroll
        for (int m = 1; m < 64; m <<= 1) { s += __shfl_xor(s, m); ss += __shfl_xor(ss, m); }
        int wid = t >> 6, lane = t & 63;
        if (lane == 0) { rs[wid] = s; rss[wid] = ss; }
        __syncthreads();
        s  = rs[0] + rs[1] + rs[2] + rs[3];
        ss = rss[0] + rss[1] + rss[2] + rss[3];
        float mu   = s * (1.0f / DIM_);
        float var  = ss * (1.0f / DIM_) - mu * mu;
        float rstd = rsqrtf(var + 1e-6f);
        const float4 gv = ((const float4*)g)[t];
        const float4 bv = ((const float4*)b)[t];
        ushort4 ov;
        ov.x = f2bf((v.x - mu) * rstd * gv.x + bv.x);
        ov.y = f2bf((v.y - mu) * rstd * gv.y + bv.y);
        ov.z = f2bf((v.z - mu) * rstd * gv.z + bv.z);
        ov.w = f2bf((v.w - mu) * rstd * gv.w + bv.w);
        ((ushort4*)(hb + row * DIM_))[t] = ov;
    } else {
        // ---------------- wqkv transpose tile: [1024][3072] f32 -> [3072][1024] bf16
        int idx = bid - 4096;                 // 0..767
        int c0 = (idx % 48) * 64, r0 = (idx / 48) * 64;
        const int R = 1024, C = 3072;
        int rl = t >> 4, cl = (t & 15) * 4;
#pragma unroll
        for (int p = 0; p < 4; p++) {
            float4 v = *(const float4*)(wqkv + (size_t)(r0 + rl + p * 16) * C + c0 + cl);
            T[cl + 0][rl + p * 16] = f2bf(v.x);
            T[cl + 1][rl + p * 16] = f2bf(v.y);
            T[cl + 2][rl + p * 16] = f2bf(v.z);
            T[cl + 3][rl + p * 16] = f2bf(v.w);
        }
        __syncthreads();
#pragma unroll
        for (int p = 0; p < 4; p++) {
            ushort4 o;
            o.x = T[rl + p * 16][cl + 0];
            o.y = T[rl + p * 16][cl + 1];
            o.z = T[rl + p * 16][cl + 2];
            o.w = T[rl + p * 16][cl + 3];
            *(ushort4*)(wqkvT + (size_t)(c0 + rl + p * 16) * R + r0 + cl) = o;
        }
    }
}

// ---------------------------------------------------------------- fp32 -> bf16 transpose (wo)
__global__ __launch_bounds__(256) void transpose_f32_bf16(
    const float* __restrict__ src, u16* __restrict__ dst, int R, int C)
{
    __shared__ u16 T[64][65];
    int c0 = blockIdx.x * 64, r0 = blockIdx.y * 64;
    int t = threadIdx.x;
    int rl = t >> 4, cl = (t & 15) * 4;
#pragma unroll
    for (int p = 0; p < 4; p++) {
        float4 v = *(const float4*)(src + (size_t)(r0 + rl + p * 16) * C + c0 + cl);
        T[cl + 0][rl + p * 16] = f2bf(v.x);
        T[cl + 1][rl + p * 16] = f2bf(v.y);
        T[cl + 2][rl + p * 16] = f2bf(v.z);
        T[cl + 3][rl + p * 16] = f2bf(v.w);
    }
    __syncthreads();
#pragma unroll
    for (int p = 0; p < 4; p++) {
        ushort4 o;
        o.x = T[rl + p * 16][cl + 0];
        o.y = T[rl + p * 16][cl + 1];
        o.z = T[rl + p * 16][cl + 2];
        o.w = T[rl + p * 16][cl + 3];
        *(ushort4*)(dst + (size_t)(c0 + rl + p * 16) * R + r0 + cl) = o;
    }
}

// ---------------------------------------------------------------- QKV GEMM 128x128 (dbuf pipeline)
__global__ __launch_bounds__(256) void qkv_gemm128(
    const u16* __restrict__ A, const u16* __restrict__ Bw,
    const float* __restrict__ bias, u16* __restrict__ qkv)
{
    __shared__ __align__(16) u16 As[2][128 * 32];
    __shared__ __align__(16) u16 Bs[2][128 * 32];
    int t = threadIdx.x;
    int bn = blockIdx.x * 128, bm = blockIdx.y * 128;
    int wid = t >> 6, lane = t & 63;
    int wm = wid >> 1, wn = wid & 1;
    int l15 = lane & 15, l4 = lane >> 4;

    f32x4 zero = {0.f, 0.f, 0.f, 0.f};
    f32x4 acc[4][4];
#pragma unroll
    for (int i = 0; i < 4; i++)
#pragma unroll
        for (int j = 0; j < 4; j++) acc[i][j] = zero;

    const u16* aSrc = A  + (size_t)(bm + wid * 32 + (lane >> 2)) * 1024 + (lane & 3) * 8;
    const u16* bSrc = Bw + (size_t)(bn + wid * 32 + (lane >> 2)) * 1024 + (lane & 3) * 8;

#define STAGE_G(bufsel, kk) do { \
        char* Ad = (char*)As + (bufsel) * 8192 + wid * 2048; \
        char* Bd = (char*)Bs + (bufsel) * 8192 + wid * 2048; \
        gload_lds16(aSrc + (kk),             (u16*)Ad); \
        gload_lds16(aSrc + (kk) + 16 * 1024, (u16*)(Ad + 1024)); \
        gload_lds16(bSrc + (kk),             (u16*)Bd); \
        gload_lds16(bSrc + (kk) + 16 * 1024, (u16*)(Bd + 1024)); \
    } while (0)

    STAGE_G(0, 0);
    __syncthreads();
    int cur = 0;
    for (int kt = 0; kt < 32; ++kt) {
        if (kt < 31) STAGE_G(cur ^ 1, (kt + 1) * 32);
        const char* Ab = (const char*)As + cur * 8192;
        const char* Bb = (const char*)Bs + cur * 8192;
        bf16x8 af[4], bf[4];
#pragma unroll
        for (int mi = 0; mi < 4; mi++)
            af[mi] = *(const bf16x8*)(Ab + (wm * 64 + mi * 16 + l15) * 64 + l4 * 16);
#pragma unroll
        for (int ni = 0; ni < 4; ni++)
            bf[ni] = *(const bf16x8*)(Bb + (wn * 64 + ni * 16 + l15) * 64 + l4 * 16);
        __builtin_amdgcn_s_setprio(1);
#pragma unroll
        for (int mi = 0; mi < 4; mi++)
#pragma unroll
            for (int ni = 0; ni < 4; ni++)
                acc[mi][ni] = __builtin_amdgcn_mfma_f32_16x16x32_bf16(af[mi], bf[ni], acc[mi][ni], 0, 0, 0);
        __builtin_amdgcn_s_setprio(0);
        __syncthreads();
        cur ^= 1;
    }
#pragma unroll
    for (int mi = 0; mi < 4; mi++)
#pragma unroll
        for (int ni = 0; ni < 4; ni++) {
            int col = bn + wn * 64 + ni * 16 + l15;
            int which = col >> 10, f = col & 1023;
            int hh = f >> 6, d = f & 63;
            float bs = bias[col];
            if (which == 2) {
                int s_base = bm + wm * 64 + mi * 16 + l4 * 4;
                int bb = s_base >> 11, s = s_base & 2047;
                ushort4 pk;
                pk.x = f2bf(acc[mi][ni][0] + bs);
                pk.y = f2bf(acc[mi][ni][1] + bs);
                pk.z = f2bf(acc[mi][ni][2] + bs);
                pk.w = f2bf(acc[mi][ni][3] + bs);
                *(ushort4*)(qkv + (size_t)2 * QKV_SZ +
                            ((size_t)(bb * 16 + hh) * 64 + d) * 2048 + s) = pk;
            } else {
                float scl = (which == 0) ? 0.18033688011112042f : 1.0f; // 0.125*log2(e)
#pragma unroll
                for (int r = 0; r < 4; r++) {
                    int row = bm + wm * 64 + mi * 16 + l4 * 4 + r;
                    int bb = row >> 11, s = row & 2047;
                    qkv[(size_t)which * QKV_SZ + ((size_t)(bb * 16 + hh) * 2048 + s) * 64 + d] =
                        f2bf((acc[mi][ni][r] + bs) * scl);
                }
            }
        }
}

// ---------------------------------------------------------------- Out GEMM 128x64 + residual
// BM=128, BN=64 -> grid (16,32)=512 blocks = 2/CU (vs 1/CU at 128x128).
// 4 waves stacked along M, each wave 32x64 (2x4 MFMA frags). Dbuf pipeline.
__global__ __launch_bounds__(256) void out_gemm128(
    const u16* __restrict__ A, const u16* __restrict__ Bw,
    const float* __restrict__ bias, const float* __restrict__ xres,
    float* __restrict__ out)
{
    __shared__ __align__(16) u16 As[2][128 * 32];
    __shared__ __align__(16) u16 Bs[2][64 * 32];
    int t = threadIdx.x;
    int bn = blockIdx.x * 64, bm = blockIdx.y * 128;
    int wid = t >> 6, lane = t & 63;
    int l15 = lane & 15, l4 = lane >> 4;

    f32x4 zero = {0.f, 0.f, 0.f, 0.f};
    f32x4 acc[2][4];
#pragma unroll
    for (int i = 0; i < 2; i++)
#pragma unroll
        for (int j = 0; j < 4; j++) acc[i][j] = zero;

    const u16* aSrc = A  + (size_t)(bm + (t >> 2)) * 1024 + (t & 3) * 8;   // rows 0..63
    const u16* bSrc = Bw + (size_t)(bn + (t >> 2)) * 1024 + (t & 3) * 8;   // rows 0..63

#define OSTG(bufsel, kk) do { \
        char* Ad = (char*)As + (bufsel) * 8192 + wid * 1024; \
        char* Bd = (char*)Bs + (bufsel) * 4096 + wid * 1024; \
        gload_lds16(aSrc + (kk),             (u16*)Ad); \
        gload_lds16(aSrc + (kk) + 64 * 1024, (u16*)(Ad + 4096)); \
        gload_lds16(bSrc + (kk),             (u16*)Bd); \
    } while (0)

    OSTG(0, 0);
    __syncthreads();
    int cur = 0;
    for (int kt = 0; kt < 32; ++kt) {
        if (kt < 31) OSTG(cur ^ 1, (kt + 1) * 32);
        const char* Ab = (const char*)As + cur * 8192;
        const char* Bb = (const char*)Bs + cur * 4096;
        bf16x8 af[2], bf[4];
#pragma unroll
        for (int mi = 0; mi < 2; mi++)
            af[mi] = *(const bf16x8*)(Ab + (wid * 32 + mi * 16 + l15) * 64 + l4 * 16);
#pragma unroll
        for (int ni = 0; ni < 4; ni++)
            bf[ni] = *(const bf16x8*)(Bb + (ni * 16 + l15) * 64 + l4 * 16);
        __builtin_amdgcn_s_setprio(1);
#pragma unroll
        for (int mi = 0; mi < 2; mi++)
#pragma unroll
            for (int ni = 0; ni < 4; ni++)
                acc[mi][ni] = __builtin_amdgcn_mfma_f32_16x16x32_bf16(af[mi], bf[ni], acc[mi][ni], 0, 0, 0);
        __builtin_amdgcn_s_setprio(0);
        __syncthreads();
        cur ^= 1;
    }
#pragma unroll
    for (int mi = 0; mi < 2; mi++)
#pragma unroll
        for (int ni = 0; ni < 4; ni++) {
            int col = bn + ni * 16 + l15;
            float bs = bias[col];
#pragma unroll
            for (int r = 0; r < 4; r++) {
                int row = bm + wid * 32 + mi * 16 + l4 * 4 + r;
                out[(size_t)row * 1024 + col] = xres[(size_t)row * 1024 + col] + acc[mi][ni][r] + bs;
            }
        }
}

// ---------------------------------------------------------------- Flash attention (unchanged, round-6-proven)
__global__ __launch_bounds__(256) void attn_kernel(
    const u16* __restrict__ qbuf, const u16* __restrict__ kbuf,
    const u16* __restrict__ vbuf, u16* __restrict__ ctx)
{
    __shared__ __align__(16) char Ks[64 * 128];
    __shared__ __align__(16) char Vt[64 * 128];
    __shared__ __align__(16) char Pb[4 * 16 * 128];

    int t = threadIdx.x, wid = t >> 6, lane = t & 63;
    int l15 = lane & 15, l4 = lane >> 4;
    int idx = blockIdx.x;
    int qt = 31 - (idx >> 5);          // longest blocks first
    int bh = idx & 31;
    int q0 = qt * 64;
    int sr = t >> 3, g = t & 7;
    int bb = bh >> 4, hh = bh & 15;
    f32x4 zero = {0.f, 0.f, 0.f, 0.f};

    const u16* Q = qbuf + (size_t)(bh * 2048 + q0 + wid * 16) * 64;
    bf16x8 aq0 = *(const bf16x8*)(Q + l15 * 64 + 8 * l4);
    bf16x8 aq1 = *(const bf16x8*)(Q + l15 * 64 + 32 + 8 * l4);

    f32x4 o[4];
#pragma unroll
    for (int f = 0; f < 4; f++) o[f] = zero;
    float m_run = -1e30f;
    float l_run = 0.f;

    int kswz = (16 * g) ^ ((sr & 7) << 4);
    char* Pw = Pb + wid * 2048;
    int prow = l15 * 128;
    int pkey = (l15 & 7) << 4;
    int qloc = wid * 16 + l15;

    const u16* Kbase = kbuf + (size_t)bh * 2048 * 64;      // [s][64]
    const u16* Vbase = vbuf + (size_t)bh * 64 * 2048;      // [d][s]

    bf16x8 ck0 = *(const bf16x8*)(Kbase + (size_t)sr * 64 + g * 8);
    bf16x8 ck1 = *(const bf16x8*)(Kbase + (size_t)(sr + 32) * 64 + g * 8);
    bf16x8 cv0 = *(const bf16x8*)(Vbase + (size_t)sr * 2048 + g * 8);
    bf16x8 cv1 = *(const bf16x8*)(Vbase + (size_t)(sr + 32) * 2048 + g * 8);

    for (int kt = 0; kt <= qt; ++kt) {
        *(bf16x8*)(Ks + sr * 128 + kswz) = ck0;
        *(bf16x8*)(Ks + (sr + 32) * 128 + kswz) = ck1;
        *(bf16x8*)(Vt + sr * 128 + kswz) = cv0;
        *(bf16x8*)(Vt + (sr + 32) * 128 + kswz) = cv1;
        {
            int nkt = (kt < qt) ? kt + 1 : qt;   // clamped -> always initialized
            const u16* Kn = Kbase + (size_t)nkt * 64 * 64;
            const u16* Vn = Vbase + (size_t)nkt * 64;
            bf16x8 a = *(const bf16x8*)(Kn + (size_t)sr * 64 + g * 8);
            bf16x8 b = *(const bf16x8*)(Kn + (size_t)(sr + 32) * 64 + g * 8);
            bf16x8 c = *(const bf16x8*)(Vn + (size_t)sr * 2048 + g * 8);
            bf16x8 d = *(const bf16x8*)(Vn + (size_t)(sr + 32) * 2048 + g * 8);
            __syncthreads();

            // ---- scores (swapped): sc[nf][r] = S[ka=nf*16+4*l4+r][q=l15]
            f32x4 sc[4];
            __builtin_amdgcn_s_setprio(1);
#pragma unroll
            for (int nf = 0; nf < 4; ++nf) {
                int krow = nf * 16 + l15;
                int kkey = (krow & 7) << 4;
                bf16x8 kb0 = *(const bf16x8*)(Ks + krow * 128 + ((16 * l4) ^ kkey));
                bf16x8 kb1 = *(const bf16x8*)(Ks + krow * 128 + ((64 + 16 * l4) ^ kkey));
                f32x4 z = zero;
                z = __builtin_amdgcn_mfma_f32_16x16x32_bf16(kb0, aq0, z, 0, 0, 0);
                z = __builtin_amdgcn_mfma_f32_16x16x32_bf16(kb1, aq1, z, 0, 0, 0);
                sc[nf] = z;
            }
            __builtin_amdgcn_s_setprio(0);

            if (kt == qt) {
#pragma unroll
                for (int nf = 0; nf < 4; nf++)
#pragma unroll
                    for (int r = 0; r < 4; r++) {
                        int ka = nf * 16 + 4 * l4 + r;
                        if (ka > qloc) sc[nf][r] = -1e30f;
                    }
            }
            // ---- local max + deferred global max
            float lmax = sc[0][0];
#pragma unroll
            for (int nf = 0; nf < 4; nf++)
#pragma unroll
                for (int r = 0; r < 4; r++) lmax = fmaxf(lmax, sc[nf][r]);
            if (__any(lmax > m_run + 10.f)) {
                float m0 = lmax;
                m0 = fmaxf(m0, __shfl_xor(m0, 16));
                m0 = fmaxf(m0, __shfl_xor(m0, 32));
                float mn = fmaxf(m_run, m0);
                float al = exp2_fast(m_run - mn);
                l_run *= al;
                m_run = mn;
                float a0 = __shfl(al, 4 * l4 + 0);
                float a1 = __shfl(al, 4 * l4 + 1);
                float a2 = __shfl(al, 4 * l4 + 2);
                float a3 = __shfl(al, 4 * l4 + 3);
#pragma unroll
                for (int f = 0; f < 4; f++) {
                    o[f][0] *= a0; o[f][1] *= a1; o[f][2] *= a2; o[f][3] *= a3;
                }
            }
            // ---- exp2 + per-lane partial sum
            float psum = 0.f;
#pragma unroll
            for (int nf = 0; nf < 4; nf++)
#pragma unroll
                for (int r = 0; r < 4; r++) {
                    float pv = exp2_fast(sc[nf][r] - m_run);
                    sc[nf][r] = pv; psum += pv;
                }
            l_run += psum;
            // ---- P pack + write (k-consecutive quad per lane)
#pragma unroll
            for (int nf = 0; nf < 4; nf++) {
                uint2 w;
                w.x = cvtpk_bf16(sc[nf][0], sc[nf][1]);
                w.y = cvtpk_bf16(sc[nf][2], sc[nf][3]);
                *(uint2*)(Pw + prow + ((nf * 32 + l4 * 8) ^ pkey)) = w;
            }
            // ---- P @ V
            __builtin_amdgcn_s_setprio(1);
#pragma unroll
            for (int kk = 0; kk < 2; kk++) {
                bf16x8 pa = *(const bf16x8*)(Pw + prow + ((64 * kk + 16 * l4) ^ pkey));
#pragma unroll
                for (int f = 0; f < 4; f++) {
                    int vrow = f * 16 + l15;
                    int vkey = (vrow & 7) << 4;
                    bf16x8 vb = *(const bf16x8*)(Vt + vrow * 128 + ((64 * kk + 16 * l4) ^ vkey));
                    o[f] = __builtin_amdgcn_mfma_f32_16x16x32_bf16(pa, vb, o[f], 0, 0, 0);
                }
            }
            __builtin_amdgcn_s_setprio(0);
            __syncthreads();
            ck0 = a; ck1 = b; cv0 = c; cv1 = d;
        }
    }
    // ---- final row-sum reduce
    l_run += __shfl_xor(l_run, 16);
    l_run += __shfl_xor(l_run, 32);
#pragma unroll
    for (int r = 0; r < 4; r++) {
        float lr = __shfl(l_run, 4 * l4 + r);
        float inv = 1.f / lr;
        int qa = q0 + wid * 16 + l4 * 4 + r;
        u16* dst = ctx + (size_t)(bb * 2048 + qa) * 1024 + hh * 64;
#pragma unroll
        for (int f = 0; f < 4; f++) dst[f * 16 + l15] = f2bf(o[f][r] * inv);
    }
}

// ----------------------------------------------------------------
extern "C" void kernel_launch(void* const* d_in, const int* in_sizes, int n_in,
                              void* d_out, int out_size, void* d_ws, size_t ws_size,
                              hipStream_t stream)
{
    const float* x    = (const float*)d_in[0];
    const float* ln_g = (const float*)d_in[1];
    const float* ln_b = (const float*)d_in[2];
    const float* wqkv = (const float*)d_in[3];
    const float* bqkv = (const float*)d_in[4];
    const float* wo   = (const float*)d_in[5];
    const float* bo   = (const float*)d_in[6];
    float* out = (float*)d_out;

    char* ws = (char*)d_ws;
    u16* hbuf  = (u16*)ws;                          // 8 MB   (LN out; later woT reuses front)
    u16* qkvb  = (u16*)(ws + 8388608);              // 24 MB  q/k head-major, v transposed
    u16* ctxb  = (u16*)(ws + 33554432);             // 8 MB   (wqkvT first, then ctx)
    u16* wqkvT = ctxb;                              // 6.29 MB (dead before attn writes ctx)
    u16* woT   = hbuf;                              // 2 MB   (hbuf dead after qkv_gemm)

    prep_kernel<<<4864, 256, 0, stream>>>(x, ln_g, ln_b, hbuf, wqkv, wqkvT);
    qkv_gemm128<<<dim3(24, 32), 256, 0, stream>>>(hbuf, wqkvT, bqkv, qkvb);
    transpose_f32_bf16<<<dim3(16, 16), 256, 0, stream>>>(wo, woT, 1024, 1024);
    attn_kernel<<<1024, 256, 0, stream>>>(
        qkvb, qkvb + QKV_SZ, qkvb + 2 * QKV_SZ, ctxb);
    out_gemm128<<<dim3(16, 32), 256, 0, stream>>>(ctxb, woT, bo, x, out);
}

// Round 9
// 115.654 us; speedup vs baseline: 1.1194x; 1.0263x over previous
//
#include <hip/hip_runtime.h>
#include <hip/hip_bf16.h>

#define B_   2
#define S_   2048
#define H_   16
#define D_   64
#define DIM_ 1024
#define QKV_SZ (32 * 2048 * 64)

typedef __attribute__((ext_vector_type(8))) short bf16x8;
typedef __attribute__((ext_vector_type(4))) float f32x4;
typedef unsigned short u16;
typedef unsigned int u32;

static __device__ __forceinline__ u16 f2bf(float f) {      // RNE
    union { float f; unsigned u; } v; v.f = f;
    unsigned u = v.u;
    unsigned r = (u + 0x7fffu + ((u >> 16) & 1u)) >> 16;
    return (u16)r;
}
static __device__ __forceinline__ float exp2_fast(float x) {
    float r; asm("v_exp_f32 %0, %1" : "=v"(r) : "v"(x)); return r;
}
static __device__ __forceinline__ u32 cvtpk_bf16(float lo, float hi) {
    u32 r; asm("v_cvt_pk_bf16_f32 %0, %1, %2" : "=v"(r) : "v"(lo), "v"(hi)); return r;
}
static __device__ __forceinline__ void gload_lds16(const u16* g, u16* l) {
    __builtin_amdgcn_global_load_lds(
        (const __attribute__((address_space(1))) void*)g,
        (__attribute__((address_space(3))) void*)l, 16, 0, 0);
}

// ---------------------------------------------------------------- prep: LN + wqkv transpose (merged)
__global__ __launch_bounds__(256) void prep_kernel(
    const float* __restrict__ x, const float* __restrict__ g,
    const float* __restrict__ b, u16* __restrict__ hb,
    const float* __restrict__ wqkv, u16* __restrict__ wqkvT)
{
    __shared__ u16 T[64][65];
    __shared__ float rs[4], rss[4];
    int bid = blockIdx.x;
    int t = threadIdx.x;
    if (bid < 4096) {
        int row = bid;
        const float4 v = ((const float4*)(x + row * DIM_))[t];
        float s  = v.x + v.y + v.z + v.w;
        float ss = v.x*v.x + v.y*v.y + v.z*v.z + v.w*v.w;
#pragma unroll
        for (int m = 1; m < 64; m <<= 1) { s += __shfl_xor(s, m); ss += __shfl_xor(ss, m); }
        int wid = t >> 6, lane = t & 63;
        if (lane == 0) { rs[wid] = s; rss[wid] = ss; }
        __syncthreads();
        s  = rs[0] + rs[1] + rs[2] + rs[3];
        ss = rss[0] + rss[1] + rss[2] + rss[3];
        float mu   = s * (1.0f / DIM_);
        float var  = ss * (1.0f / DIM_) - mu * mu;
        float rstd = rsqrtf(var + 1e-6f);
        const float4 gv = ((const float4*)g)[t];
        const float4 bv = ((const float4*)b)[t];
        ushort4 ov;
        ov.x = f2bf((v.x - mu) * rstd * gv.x + bv.x);
        ov.y = f2bf((v.y - mu) * rstd * gv.y + bv.y);
        ov.z = f2bf((v.z - mu) * rstd * gv.z + bv.z);
        ov.w = f2bf((v.w - mu) * rstd * gv.w + bv.w);
        ((ushort4*)(hb + row * DIM_))[t] = ov;
    } else {
        int idx = bid - 4096;                 // 0..767
        int c0 = (idx % 48) * 64, r0 = (idx / 48) * 64;
        const int R = 1024, C = 3072;
        int rl = t >> 4, cl = (t & 15) * 4;
#pragma unroll
        for (int p = 0; p < 4; p++) {
            float4 v = *(const float4*)(wqkv + (size_t)(r0 + rl + p * 16) * C + c0 + cl);
            T[cl + 0][rl + p * 16] = f2bf(v.x);
            T[cl + 1][rl + p * 16] = f2bf(v.y);
            T[cl + 2][rl + p * 16] = f2bf(v.z);
            T[cl + 3][rl + p * 16] = f2bf(v.w);
        }
        __syncthreads();
#pragma unroll
        for (int p = 0; p < 4; p++) {
            ushort4 o;
            o.x = T[rl + p * 16][cl + 0];
            o.y = T[rl + p * 16][cl + 1];
            o.z = T[rl + p * 16][cl + 2];
            o.w = T[rl + p * 16][cl + 3];
            *(ushort4*)(wqkvT + (size_t)(c0 + rl + p * 16) * R + r0 + cl) = o;
        }
    }
}

// ---------------------------------------------------------------- fp32 -> bf16 transpose (wo)
__global__ __launch_bounds__(256) void transpose_f32_bf16(
    const float* __restrict__ src, u16* __restrict__ dst, int R, int C)
{
    __shared__ u16 T[64][65];
    int c0 = blockIdx.x * 64, r0 = blockIdx.y * 64;
    int t = threadIdx.x;
    int rl = t >> 4, cl = (t & 15) * 4;
#pragma unroll
    for (int p = 0; p < 4; p++) {
        float4 v = *(const float4*)(src + (size_t)(r0 + rl + p * 16) * C + c0 + cl);
        T[cl + 0][rl + p * 16] = f2bf(v.x);
        T[cl + 1][rl + p * 16] = f2bf(v.y);
        T[cl + 2][rl + p * 16] = f2bf(v.z);
        T[cl + 3][rl + p * 16] = f2bf(v.w);
    }
    __syncthreads();
#pragma unroll
    for (int p = 0; p < 4; p++) {
        ushort4 o;
        o.x = T[rl + p * 16][cl + 0];
        o.y = T[rl + p * 16][cl + 1];
        o.z = T[rl + p * 16][cl + 2];
        o.w = T[rl + p * 16][cl + 3];
        *(ushort4*)(dst + (size_t)(c0 + rl + p * 16) * R + r0 + cl) = o;
    }
}

// ---------------------------------------------------------------- QKV GEMM 128x128
// 3-buffer LDS pipeline, counted vmcnt (loads span the barrier — T3/T4).
// Hazards: RAW — each wave s_waitcnt vmcnt(4) (own buf-cur loads done) BEFORE
// s_barrier, so post-barrier all contributions are complete. WAR — STAGE at
// iter kt overwrites buf[(kt-1)%3]; its readers retired ds_reads (consumed by
// MFMA) before reaching barrier(kt), and STAGE issues after barrier(kt).
__global__ __launch_bounds__(256) void qkv_gemm128(
    const u16* __restrict__ A, const u16* __restrict__ Bw,
    const float* __restrict__ bias, u16* __restrict__ qkv)
{
    __shared__ __align__(16) u16 As[3][128 * 32];
    __shared__ __align__(16) u16 Bs[3][128 * 32];
    int t = threadIdx.x;
    int bn = blockIdx.x * 128, bm = blockIdx.y * 128;
    int wid = t >> 6, lane = t & 63;
    int wm = wid >> 1, wn = wid & 1;
    int l15 = lane & 15, l4 = lane >> 4;

    f32x4 zero = {0.f, 0.f, 0.f, 0.f};
    f32x4 acc[4][4];
#pragma unroll
    for (int i = 0; i < 4; i++)
#pragma unroll
        for (int j = 0; j < 4; j++) acc[i][j] = zero;

    const u16* aSrc = A  + (size_t)(bm + wid * 32 + (lane >> 2)) * 1024 + (lane & 3) * 8;
    const u16* bSrc = Bw + (size_t)(bn + wid * 32 + (lane >> 2)) * 1024 + (lane & 3) * 8;

#define STAGE_Q(bufsel, kk) do { \
        char* Ad = (char*)As + (bufsel) * 8192 + wid * 2048; \
        char* Bd = (char*)Bs + (bufsel) * 8192 + wid * 2048; \
        gload_lds16(aSrc + (kk),             (u16*)Ad); \
        gload_lds16(aSrc + (kk) + 16 * 1024, (u16*)(Ad + 1024)); \
        gload_lds16(bSrc + (kk),             (u16*)Bd); \
        gload_lds16(bSrc + (kk) + 16 * 1024, (u16*)(Bd + 1024)); \
    } while (0)

    STAGE_Q(0, 0);
    STAGE_Q(1, 32);
    int cur = 0;
    for (int kt = 0; kt < 32; ++kt) {
        if (kt < 31) asm volatile("s_waitcnt vmcnt(4)" ::: "memory");
        else         asm volatile("s_waitcnt vmcnt(0)" ::: "memory");
        __builtin_amdgcn_s_barrier();
        asm volatile("" ::: "memory");
        if (kt < 30) {
            int sb = cur + 2; if (sb >= 3) sb -= 3;
            STAGE_Q(sb, (kt + 2) * 32);
        }
        const char* Ab = (const char*)As + cur * 8192;
        const char* Bb = (const char*)Bs + cur * 8192;
        bf16x8 af[4], bf[4];
#pragma unroll
        for (int mi = 0; mi < 4; mi++)
            af[mi] = *(const bf16x8*)(Ab + (wm * 64 + mi * 16 + l15) * 64 + l4 * 16);
#pragma unroll
        for (int ni = 0; ni < 4; ni++)
            bf[ni] = *(const bf16x8*)(Bb + (wn * 64 + ni * 16 + l15) * 64 + l4 * 16);
        __builtin_amdgcn_s_setprio(1);
#pragma unroll
        for (int mi = 0; mi < 4; mi++)
#pragma unroll
            for (int ni = 0; ni < 4; ni++)
                acc[mi][ni] = __builtin_amdgcn_mfma_f32_16x16x32_bf16(af[mi], bf[ni], acc[mi][ni], 0, 0, 0);
        __builtin_amdgcn_s_setprio(0);
        asm volatile("" ::: "memory");
        cur = (cur >= 2) ? 0 : cur + 1;
    }
#pragma unroll
    for (int mi = 0; mi < 4; mi++)
#pragma unroll
        for (int ni = 0; ni < 4; ni++) {
            int col = bn + wn * 64 + ni * 16 + l15;
            int which = col >> 10, f = col & 1023;
            int hh = f >> 6, d = f & 63;
            float bs = bias[col];
            if (which == 2) {
                int s_base = bm + wm * 64 + mi * 16 + l4 * 4;
                int bb = s_base >> 11, s = s_base & 2047;
                ushort4 pk;
                pk.x = f2bf(acc[mi][ni][0] + bs);
                pk.y = f2bf(acc[mi][ni][1] + bs);
                pk.z = f2bf(acc[mi][ni][2] + bs);
                pk.w = f2bf(acc[mi][ni][3] + bs);
                *(ushort4*)(qkv + (size_t)2 * QKV_SZ +
                            ((size_t)(bb * 16 + hh) * 64 + d) * 2048 + s) = pk;
            } else {
                float scl = (which == 0) ? 0.18033688011112042f : 1.0f; // 0.125*log2(e)
#pragma unroll
                for (int r = 0; r < 4; r++) {
                    int row = bm + wm * 64 + mi * 16 + l4 * 4 + r;
                    int bb = row >> 11, s = row & 2047;
                    qkv[(size_t)which * QKV_SZ + ((size_t)(bb * 16 + hh) * 2048 + s) * 64 + d] =
                        f2bf((acc[mi][ni][r] + bs) * scl);
                }
            }
        }
}

// ---------------------------------------------------------------- Out GEMM 128x64 + residual
// Same counted-vmcnt 3-buffer pipeline; 3 loads/stage -> vmcnt(3).
__global__ __launch_bounds__(256) void out_gemm128(
    const u16* __restrict__ A, const u16* __restrict__ Bw,
    const float* __restrict__ bias, const float* __restrict__ xres,
    float* __restrict__ out)
{
    __shared__ __align__(16) u16 As[3][128 * 32];
    __shared__ __align__(16) u16 Bs[3][64 * 32];
    int t = threadIdx.x;
    int bn = blockIdx.x * 64, bm = blockIdx.y * 128;
    int wid = t >> 6, lane = t & 63;
    int l15 = lane & 15, l4 = lane >> 4;

    f32x4 zero = {0.f, 0.f, 0.f, 0.f};
    f32x4 acc[2][4];
#pragma unroll
    for (int i = 0; i < 2; i++)
#pragma unroll
        for (int j = 0; j < 4; j++) acc[i][j] = zero;

    const u16* aSrc = A  + (size_t)(bm + (t >> 2)) * 1024 + (t & 3) * 8;   // rows 0..63
    const u16* bSrc = Bw + (size_t)(bn + (t >> 2)) * 1024 + (t & 3) * 8;   // rows 0..63

#define STAGE_O(bufsel, kk) do { \
        char* Ad = (char*)As + (bufsel) * 8192 + wid * 1024; \
        char* Bd = (char*)Bs + (bufsel) * 4096 + wid * 1024; \
        gload_lds16(aSrc + (kk),             (u16*)Ad); \
        gload_lds16(aSrc + (kk) + 64 * 1024, (u16*)(Ad + 4096)); \
        gload_lds16(bSrc + (kk),             (u16*)Bd); \
    } while (0)

    STAGE_O(0, 0);
    STAGE_O(1, 32);
    int cur = 0;
    for (int kt = 0; kt < 32; ++kt) {
        if (kt < 31) asm volatile("s_waitcnt vmcnt(3)" ::: "memory");
        else         asm volatile("s_waitcnt vmcnt(0)" ::: "memory");
        __builtin_amdgcn_s_barrier();
        asm volatile("" ::: "memory");
        if (kt < 30) {
            int sb = cur + 2; if (sb >= 3) sb -= 3;
            STAGE_O(sb, (kt + 2) * 32);
        }
        const char* Ab = (const char*)As + cur * 8192;
        const char* Bb = (const char*)Bs + cur * 4096;
        bf16x8 af[2], bf[4];
#pragma unroll
        for (int mi = 0; mi < 2; mi++)
            af[mi] = *(const bf16x8*)(Ab + (wid * 32 + mi * 16 + l15) * 64 + l4 * 16);
#pragma unroll
        for (int ni = 0; ni < 4; ni++)
            bf[ni] = *(const bf16x8*)(Bb + (ni * 16 + l15) * 64 + l4 * 16);
        __builtin_amdgcn_s_setprio(1);
#pragma unroll
        for (int mi = 0; mi < 2; mi++)
#pragma unroll
            for (int ni = 0; ni < 4; ni++)
                acc[mi][ni] = __builtin_amdgcn_mfma_f32_16x16x32_bf16(af[mi], bf[ni], acc[mi][ni], 0, 0, 0);
        __builtin_amdgcn_s_setprio(0);
        asm volatile("" ::: "memory");
        cur = (cur >= 2) ? 0 : cur + 1;
    }
#pragma unroll
    for (int mi = 0; mi < 2; mi++)
#pragma unroll
        for (int ni = 0; ni < 4; ni++) {
            int col = bn + ni * 16 + l15;
            float bs = bias[col];
#pragma unroll
            for (int r = 0; r < 4; r++) {
                int row = bm + wid * 32 + mi * 16 + l4 * 4 + r;
                out[(size_t)row * 1024 + col] = xres[(size_t)row * 1024 + col] + acc[mi][ni][r] + bs;
            }
        }
}

// ---------------------------------------------------------------- Flash attention (unchanged, round-6-proven)
__global__ __launch_bounds__(256) void attn_kernel(
    const u16* __restrict__ qbuf, const u16* __restrict__ kbuf,
    const u16* __restrict__ vbuf, u16* __restrict__ ctx)
{
    __shared__ __align__(16) char Ks[64 * 128];
    __shared__ __align__(16) char Vt[64 * 128];
    __shared__ __align__(16) char Pb[4 * 16 * 128];

    int t = threadIdx.x, wid = t >> 6, lane = t & 63;
    int l15 = lane & 15, l4 = lane >> 4;
    int idx = blockIdx.x;
    int qt = 31 - (idx >> 5);          // longest blocks first
    int bh = idx & 31;
    int q0 = qt * 64;
    int sr = t >> 3, g = t & 7;
    int bb = bh >> 4, hh = bh & 15;
    f32x4 zero = {0.f, 0.f, 0.f, 0.f};

    const u16* Q = qbuf + (size_t)(bh * 2048 + q0 + wid * 16) * 64;
    bf16x8 aq0 = *(const bf16x8*)(Q + l15 * 64 + 8 * l4);
    bf16x8 aq1 = *(const bf16x8*)(Q + l15 * 64 + 32 + 8 * l4);

    f32x4 o[4];
#pragma unroll
    for (int f = 0; f < 4; f++) o[f] = zero;
    float m_run = -1e30f;
    float l_run = 0.f;

    int kswz = (16 * g) ^ ((sr & 7) << 4);
    char* Pw = Pb + wid * 2048;
    int prow = l15 * 128;
    int pkey = (l15 & 7) << 4;
    int qloc = wid * 16 + l15;

    const u16* Kbase = kbuf + (size_t)bh * 2048 * 64;      // [s][64]
    const u16* Vbase = vbuf + (size_t)bh * 64 * 2048;      // [d][s]

    bf16x8 ck0 = *(const bf16x8*)(Kbase + (size_t)sr * 64 + g * 8);
    bf16x8 ck1 = *(const bf16x8*)(Kbase + (size_t)(sr + 32) * 64 + g * 8);
    bf16x8 cv0 = *(const bf16x8*)(Vbase + (size_t)sr * 2048 + g * 8);
    bf16x8 cv1 = *(const bf16x8*)(Vbase + (size_t)(sr + 32) * 2048 + g * 8);

    for (int kt = 0; kt <= qt; ++kt) {
        *(bf16x8*)(Ks + sr * 128 + kswz) = ck0;
        *(bf16x8*)(Ks + (sr + 32) * 128 + kswz) = ck1;
        *(bf16x8*)(Vt + sr * 128 + kswz) = cv0;
        *(bf16x8*)(Vt + (sr + 32) * 128 + kswz) = cv1;
        {
            int nkt = (kt < qt) ? kt + 1 : qt;   // clamped -> always initialized
            const u16* Kn = Kbase + (size_t)nkt * 64 * 64;
            const u16* Vn = Vbase + (size_t)nkt * 64;
            bf16x8 a = *(const bf16x8*)(Kn + (size_t)sr * 64 + g * 8);
            bf16x8 b = *(const bf16x8*)(Kn + (size_t)(sr + 32) * 64 + g * 8);
            bf16x8 c = *(const bf16x8*)(Vn + (size_t)sr * 2048 + g * 8);
            bf16x8 d = *(const bf16x8*)(Vn + (size_t)(sr + 32) * 2048 + g * 8);
            __syncthreads();

            // ---- scores (swapped): sc[nf][r] = S[ka=nf*16+4*l4+r][q=l15]
            f32x4 sc[4];
            __builtin_amdgcn_s_setprio(1);
#pragma unroll
            for (int nf = 0; nf < 4; ++nf) {
                int krow = nf * 16 + l15;
                int kkey = (krow & 7) << 4;
                bf16x8 kb0 = *(const bf16x8*)(Ks + krow * 128 + ((16 * l4) ^ kkey));
                bf16x8 kb1 = *(const bf16x8*)(Ks + krow * 128 + ((64 + 16 * l4) ^ kkey));
                f32x4 z = zero;
                z = __builtin_amdgcn_mfma_f32_16x16x32_bf16(kb0, aq0, z, 0, 0, 0);
                z = __builtin_amdgcn_mfma_f32_16x16x32_bf16(kb1, aq1, z, 0, 0, 0);
                sc[nf] = z;
            }
            __builtin_amdgcn_s_setprio(0);

            if (kt == qt) {
#pragma unroll
                for (int nf = 0; nf < 4; nf++)
#pragma unroll
                    for (int r = 0; r < 4; r++) {
                        int ka = nf * 16 + 4 * l4 + r;
                        if (ka > qloc) sc[nf][r] = -1e30f;
                    }
            }
            // ---- local max + deferred global max
            float lmax = sc[0][0];
#pragma unroll
            for (int nf = 0; nf < 4; nf++)
#pragma unroll
                for (int r = 0; r < 4; r++) lmax = fmaxf(lmax, sc[nf][r]);
            if (__any(lmax > m_run + 10.f)) {
                float m0 = lmax;
                m0 = fmaxf(m0, __shfl_xor(m0, 16));
                m0 = fmaxf(m0, __shfl_xor(m0, 32));
                float mn = fmaxf(m_run, m0);
                float al = exp2_fast(m_run - mn);
                l_run *= al;
                m_run = mn;
                float a0 = __shfl(al, 4 * l4 + 0);
                float a1 = __shfl(al, 4 * l4 + 1);
                float a2 = __shfl(al, 4 * l4 + 2);
                float a3 = __shfl(al, 4 * l4 + 3);
#pragma unroll
                for (int f = 0; f < 4; f++) {
                    o[f][0] *= a0; o[f][1] *= a1; o[f][2] *= a2; o[f][3] *= a3;
                }
            }
            // ---- exp2 + per-lane partial sum
            float psum = 0.f;
#pragma unroll
            for (int nf = 0; nf < 4; nf++)
#pragma unroll
                for (int r = 0; r < 4; r++) {
                    float pv = exp2_fast(sc[nf][r] - m_run);
                    sc[nf][r] = pv; psum += pv;
                }
            l_run += psum;
            // ---- P pack + write (k-consecutive quad per lane)
#pragma unroll
            for (int nf = 0; nf < 4; nf++) {
                uint2 w;
                w.x = cvtpk_bf16(sc[nf][0], sc[nf][1]);
                w.y = cvtpk_bf16(sc[nf][2], sc[nf][3]);
                *(uint2*)(Pw + prow + ((nf * 32 + l4 * 8) ^ pkey)) = w;
            }
            // ---- P @ V
            __builtin_amdgcn_s_setprio(1);
#pragma unroll
            for (int kk = 0; kk < 2; kk++) {
                bf16x8 pa = *(const bf16x8*)(Pw + prow + ((64 * kk + 16 * l4) ^ pkey));
#pragma unroll
                for (int f = 0; f < 4; f++) {
                    int vrow = f * 16 + l15;
                    int vkey = (vrow & 7) << 4;
                    bf16x8 vb = *(const bf16x8*)(Vt + vrow * 128 + ((64 * kk + 16 * l4) ^ vkey));
                    o[f] = __builtin_amdgcn_mfma_f32_16x16x32_bf16(pa, vb, o[f], 0, 0, 0);
                }
            }
            __builtin_amdgcn_s_setprio(0);
            __syncthreads();
            ck0 = a; ck1 = b; cv0 = c; cv1 = d;
        }
    }
    // ---- final row-sum reduce
    l_run += __shfl_xor(l_run, 16);
    l_run += __shfl_xor(l_run, 32);
#pragma unroll
    for (int r = 0; r < 4; r++) {
        float lr = __shfl(l_run, 4 * l4 + r);
        float inv = 1.f / lr;
        int qa = q0 + wid * 16 + l4 * 4 + r;
        u16* dst = ctx + (size_t)(bb * 2048 + qa) * 1024 + hh * 64;
#pragma unroll
        for (int f = 0; f < 4; f++) dst[f * 16 + l15] = f2bf(o[f][r] * inv);
    }
}

// ----------------------------------------------------------------
extern "C" void kernel_launch(void* const* d_in, const int* in_sizes, int n_in,
                              void* d_out, int out_size, void* d_ws, size_t ws_size,
                              hipStream_t stream)
{
    const float* x    = (const float*)d_in[0];
    const float* ln_g = (const float*)d_in[1];
    const float* ln_b = (const float*)d_in[2];
    const float* wqkv = (const float*)d_in[3];
    const float* bqkv = (const float*)d_in[4];
    const float* wo   = (const float*)d_in[5];
    const float* bo   = (const float*)d_in[6];
    float* out = (float*)d_out;

    char* ws = (char*)d_ws;
    u16* hbuf  = (u16*)ws;                          // 8 MB   (LN out; later woT reuses front)
    u16* qkvb  = (u16*)(ws + 8388608);              // 24 MB  q/k head-major, v transposed
    u16* ctxb  = (u16*)(ws + 33554432);             // 8 MB   (wqkvT first, then ctx)
    u16* wqkvT = ctxb;                              // 6.29 MB (dead before attn writes ctx)
    u16* woT   = hbuf;                              // 2 MB   (hbuf dead after qkv_gemm)

    prep_kernel<<<4864, 256, 0, stream>>>(x, ln_g, ln_b, hbuf, wqkv, wqkvT);
    qkv_gemm128<<<dim3(24, 32), 256, 0, stream>>>(hbuf, wqkvT, bqkv, qkvb);
    transpose_f32_bf16<<<dim3(16, 16), 256, 0, stream>>>(wo, woT, 1024, 1024);
    attn_kernel<<<1024, 256, 0, stream>>>(
        qkvb, qkvb + QKV_SZ, qkvb + 2 * QKV_SZ, ctxb);
    out_gemm128<<<dim3(16, 32), 256, 0, stream>>>(ctxb, woT, bo, x, out);
}

// Round 10
// 114.452 us; speedup vs baseline: 1.1311x; 1.0105x over previous
//
#include <hip/hip_runtime.h>
#include <hip/hip_bf16.h>

#define B_   2
#define S_   2048
#define H_   16
#define D_   64
#define DIM_ 1024
#define QKV_SZ (32 * 2048 * 64)

typedef __attribute__((ext_vector_type(8))) short bf16x8;
typedef __attribute__((ext_vector_type(4))) float f32x4;
typedef unsigned short u16;
typedef unsigned int u32;

static __device__ __forceinline__ u16 f2bf(float f) {      // RNE
    union { float f; unsigned u; } v; v.f = f;
    unsigned u = v.u;
    unsigned r = (u + 0x7fffu + ((u >> 16) & 1u)) >> 16;
    return (u16)r;
}
static __device__ __forceinline__ float exp2_fast(float x) {
    float r; asm("v_exp_f32 %0, %1" : "=v"(r) : "v"(x)); return r;
}
static __device__ __forceinline__ u32 cvtpk_bf16(float lo, float hi) {
    u32 r; asm("v_cvt_pk_bf16_f32 %0, %1, %2" : "=v"(r) : "v"(lo), "v"(hi)); return r;
}
static __device__ __forceinline__ void gload_lds16(const u16* g, u16* l) {
    __builtin_amdgcn_global_load_lds(
        (const __attribute__((address_space(1))) void*)g,
        (__attribute__((address_space(3))) void*)l, 16, 0, 0);
}

// ---------------------------------------------------------------- prep: LN + wqkv^T + wo^T (merged)
__global__ __launch_bounds__(256) void prep_kernel(
    const float* __restrict__ x, const float* __restrict__ g,
    const float* __restrict__ b, u16* __restrict__ hb,
    const float* __restrict__ wqkv, u16* __restrict__ wqkvT,
    const float* __restrict__ wo, u16* __restrict__ woT)
{
    __shared__ u16 T[64][65];
    __shared__ float rs[4], rss[4];
    int bid = blockIdx.x;
    int t = threadIdx.x;
    if (bid < 4096) {
        // ---------------- LayerNorm row
        int row = bid;
        const float4 v = ((const float4*)(x + row * DIM_))[t];
        float s  = v.x + v.y + v.z + v.w;
        float ss = v.x*v.x + v.y*v.y + v.z*v.z + v.w*v.w;
#pragma unroll
        for (int m = 1; m < 64; m <<= 1) { s += __shfl_xor(s, m); ss += __shfl_xor(ss, m); }
        int wid = t >> 6, lane = t & 63;
        if (lane == 0) { rs[wid] = s; rss[wid] = ss; }
        __syncthreads();
        s  = rs[0] + rs[1] + rs[2] + rs[3];
        ss = rss[0] + rss[1] + rss[2] + rss[3];
        float mu   = s * (1.0f / DIM_);
        float var  = ss * (1.0f / DIM_) - mu * mu;
        float rstd = rsqrtf(var + 1e-6f);
        const float4 gv = ((const float4*)g)[t];
        const float4 bv = ((const float4*)b)[t];
        ushort4 ov;
        ov.x = f2bf((v.x - mu) * rstd * gv.x + bv.x);
        ov.y = f2bf((v.y - mu) * rstd * gv.y + bv.y);
        ov.z = f2bf((v.z - mu) * rstd * gv.z + bv.z);
        ov.w = f2bf((v.w - mu) * rstd * gv.w + bv.w);
        ((ushort4*)(hb + row * DIM_))[t] = ov;
    } else {
        // ---------------- transpose tile (wqkv or wo)
        const float* src; u16* dst; int R, C, c0, r0;
        if (bid < 4864) {
            int idx = bid - 4096;                 // 0..767
            src = wqkv; dst = wqkvT; R = 1024; C = 3072;
            c0 = (idx % 48) * 64; r0 = (idx / 48) * 64;
        } else {
            int idx = bid - 4864;                 // 0..255
            src = wo; dst = woT; R = 1024; C = 1024;
            c0 = (idx % 16) * 64; r0 = (idx / 16) * 64;
        }
        int rl = t >> 4, cl = (t & 15) * 4;
#pragma unroll
        for (int p = 0; p < 4; p++) {
            float4 v = *(const float4*)(src + (size_t)(r0 + rl + p * 16) * C + c0 + cl);
            T[cl + 0][rl + p * 16] = f2bf(v.x);
            T[cl + 1][rl + p * 16] = f2bf(v.y);
            T[cl + 2][rl + p * 16] = f2bf(v.z);
            T[cl + 3][rl + p * 16] = f2bf(v.w);
        }
        __syncthreads();
#pragma unroll
        for (int p = 0; p < 4; p++) {
            ushort4 o;
            o.x = T[rl + p * 16][cl + 0];
            o.y = T[rl + p * 16][cl + 1];
            o.z = T[rl + p * 16][cl + 2];
            o.w = T[rl + p * 16][cl + 3];
            *(ushort4*)(dst + (size_t)(c0 + rl + p * 16) * R + r0 + cl) = o;
        }
    }
}

// ---------------------------------------------------------------- QKV GEMM 128x128 (dbuf pipeline)
// LDS swizzle: source col element ^= ((row>>1)&3), read byte-offset ^= ((l15>>1)&3)<<4.
// Bijective per 64B LDS row; makes 8-lane b128 read groups hit 8 distinct 16B slots.
__global__ __launch_bounds__(256) void qkv_gemm128(
    const u16* __restrict__ A, const u16* __restrict__ Bw,
    const float* __restrict__ bias, u16* __restrict__ qkv)
{
    __shared__ __align__(16) u16 As[2][128 * 32];
    __shared__ __align__(16) u16 Bs[2][128 * 32];
    int t = threadIdx.x;
    int bn = blockIdx.x * 128, bm = blockIdx.y * 128;
    int wid = t >> 6, lane = t & 63;
    int wm = wid >> 1, wn = wid & 1;
    int l15 = lane & 15, l4 = lane >> 4;

    f32x4 zero = {0.f, 0.f, 0.f, 0.f};
    f32x4 acc[4][4];
#pragma unroll
    for (int i = 0; i < 4; i++)
#pragma unroll
        for (int j = 0; j < 4; j++) acc[i][j] = zero;

    // staged rows r1 = wid*32 + (lane>>2) (and r1+16); swizzle key (r>>1)&3 = (lane>>3)&3
    int scol = ((lane & 3) ^ ((lane >> 3) & 3)) * 8;
    const u16* aSrc = A  + (size_t)(bm + wid * 32 + (lane >> 2)) * 1024 + scol;
    const u16* bSrc = Bw + (size_t)(bn + wid * 32 + (lane >> 2)) * 1024 + scol;
    int rdk = ((l15 >> 1) & 3) << 4;        // read-side key (byte)

#define STAGE_G(bufsel, kk) do { \
        char* Ad = (char*)As + (bufsel) * 8192 + wid * 2048; \
        char* Bd = (char*)Bs + (bufsel) * 8192 + wid * 2048; \
        gload_lds16(aSrc + (kk),             (u16*)Ad); \
        gload_lds16(aSrc + (kk) + 16 * 1024, (u16*)(Ad + 1024)); \
        gload_lds16(bSrc + (kk),             (u16*)Bd); \
        gload_lds16(bSrc + (kk) + 16 * 1024, (u16*)(Bd + 1024)); \
    } while (0)

    STAGE_G(0, 0);
    __syncthreads();
    int cur = 0;
    for (int kt = 0; kt < 32; ++kt) {
        if (kt < 31) STAGE_G(cur ^ 1, (kt + 1) * 32);
        const char* Ab = (const char*)As + cur * 8192;
        const char* Bb = (const char*)Bs + cur * 8192;
        bf16x8 af[4], bf[4];
#pragma unroll
        for (int mi = 0; mi < 4; mi++)
            af[mi] = *(const bf16x8*)(Ab + (wm * 64 + mi * 16 + l15) * 64 + (l4 * 16 ^ rdk));
#pragma unroll
        for (int ni = 0; ni < 4; ni++)
            bf[ni] = *(const bf16x8*)(Bb + (wn * 64 + ni * 16 + l15) * 64 + (l4 * 16 ^ rdk));
        __builtin_amdgcn_s_setprio(1);
#pragma unroll
        for (int mi = 0; mi < 4; mi++)
#pragma unroll
            for (int ni = 0; ni < 4; ni++)
                acc[mi][ni] = __builtin_amdgcn_mfma_f32_16x16x32_bf16(af[mi], bf[ni], acc[mi][ni], 0, 0, 0);
        __builtin_amdgcn_s_setprio(0);
        __syncthreads();
        cur ^= 1;
    }
#pragma unroll
    for (int mi = 0; mi < 4; mi++)
#pragma unroll
        for (int ni = 0; ni < 4; ni++) {
            int col = bn + wn * 64 + ni * 16 + l15;
            int which = col >> 10, f = col & 1023;
            int hh = f >> 6, d = f & 63;
            float bs = bias[col];
            if (which == 2) {
                int s_base = bm + wm * 64 + mi * 16 + l4 * 4;
                int bb = s_base >> 11, s = s_base & 2047;
                ushort4 pk;
                pk.x = f2bf(acc[mi][ni][0] + bs);
                pk.y = f2bf(acc[mi][ni][1] + bs);
                pk.z = f2bf(acc[mi][ni][2] + bs);
                pk.w = f2bf(acc[mi][ni][3] + bs);
                *(ushort4*)(qkv + (size_t)2 * QKV_SZ +
                            ((size_t)(bb * 16 + hh) * 64 + d) * 2048 + s) = pk;
            } else {
                float scl = (which == 0) ? 0.18033688011112042f : 1.0f; // 0.125*log2(e)
#pragma unroll
                for (int r = 0; r < 4; r++) {
                    int row = bm + wm * 64 + mi * 16 + l4 * 4 + r;
                    int bb = row >> 11, s = row & 2047;
                    qkv[(size_t)which * QKV_SZ + ((size_t)(bb * 16 + hh) * 2048 + s) * 64 + d] =
                        f2bf((acc[mi][ni][r] + bs) * scl);
                }
            }
        }
}

// ---------------------------------------------------------------- Out GEMM 128x64 + residual
__global__ __launch_bounds__(256) void out_gemm128(
    const u16* __restrict__ A, const u16* __restrict__ Bw,
    const float* __restrict__ bias, const float* __restrict__ xres,
    float* __restrict__ out)
{
    __shared__ __align__(16) u16 As[2][128 * 32];
    __shared__ __align__(16) u16 Bs[2][64 * 32];
    int t = threadIdx.x;
    int bn = blockIdx.x * 64, bm = blockIdx.y * 128;
    int wid = t >> 6, lane = t & 63;
    int l15 = lane & 15, l4 = lane >> 4;

    f32x4 zero = {0.f, 0.f, 0.f, 0.f};
    f32x4 acc[2][4];
#pragma unroll
    for (int i = 0; i < 2; i++)
#pragma unroll
        for (int j = 0; j < 4; j++) acc[i][j] = zero;

    // staged rows r = t>>2 (and r+64); key = (t>>3)&3 (same for +64)
    int scol = ((t & 3) ^ ((t >> 3) & 3)) * 8;
    const u16* aSrc = A  + (size_t)(bm + (t >> 2)) * 1024 + scol;
    const u16* bSrc = Bw + (size_t)(bn + (t >> 2)) * 1024 + scol;
    int rdk = ((l15 >> 1) & 3) << 4;

#define OSTG(bufsel, kk) do { \
        char* Ad = (char*)As + (bufsel) * 8192 + wid * 1024; \
        char* Bd = (char*)Bs + (bufsel) * 4096 + wid * 1024; \
        gload_lds16(aSrc + (kk),             (u16*)Ad); \
        gload_lds16(aSrc + (kk) + 64 * 1024, (u16*)(Ad + 4096)); \
        gload_lds16(bSrc + (kk),             (u16*)Bd); \
    } while (0)

    OSTG(0, 0);
    __syncthreads();
    int cur = 0;
    for (int kt = 0; kt < 32; ++kt) {
        if (kt < 31) OSTG(cur ^ 1, (kt + 1) * 32);
        const char* Ab = (const char*)As + cur * 8192;
        const char* Bb = (const char*)Bs + cur * 4096;
        bf16x8 af[2], bf[4];
#pragma unroll
        for (int mi = 0; mi < 2; mi++)
            af[mi] = *(const bf16x8*)(Ab + (wid * 32 + mi * 16 + l15) * 64 + (l4 * 16 ^ rdk));
#pragma unroll
        for (int ni = 0; ni < 4; ni++)
            bf[ni] = *(const bf16x8*)(Bb + (ni * 16 + l15) * 64 + (l4 * 16 ^ rdk));
        __builtin_amdgcn_s_setprio(1);
#pragma unroll
        for (int mi = 0; mi < 2; mi++)
#pragma unroll
            for (int ni = 0; ni < 4; ni++)
                acc[mi][ni] = __builtin_amdgcn_mfma_f32_16x16x32_bf16(af[mi], bf[ni], acc[mi][ni], 0, 0, 0);
        __builtin_amdgcn_s_setprio(0);
        __syncthreads();
        cur ^= 1;
    }
#pragma unroll
    for (int mi = 0; mi < 2; mi++)
#pragma unroll
        for (int ni = 0; ni < 4; ni++) {
            int col = bn + ni * 16 + l15;
            float bs = bias[col];
#pragma unroll
            for (int r = 0; r < 4; r++) {
                int row = bm + wid * 32 + mi * 16 + l4 * 4 + r;
                out[(size_t)row * 1024 + col] = xres[(size_t)row * 1024 + col] + acc[mi][ni][r] + bs;
            }
        }
}

// ---------------------------------------------------------------- Flash attention (round-6-proven)
__global__ __launch_bounds__(256) void attn_kernel(
    const u16* __restrict__ qbuf, const u16* __restrict__ kbuf,
    const u16* __restrict__ vbuf, u16* __restrict__ ctx)
{
    __shared__ __align__(16) char Ks[64 * 128];
    __shared__ __align__(16) char Vt[64 * 128];
    __shared__ __align__(16) char Pb[4 * 16 * 128];

    int t = threadIdx.x, wid = t >> 6, lane = t & 63;
    int l15 = lane & 15, l4 = lane >> 4;
    int idx = blockIdx.x;
    int qt = 31 - (idx >> 5);          // longest blocks first
    int bh = idx & 31;
    int q0 = qt * 64;
    int sr = t >> 3, g = t & 7;
    int bb = bh >> 4, hh = bh & 15;
    f32x4 zero = {0.f, 0.f, 0.f, 0.f};

    const u16* Q = qbuf + (size_t)(bh * 2048 + q0 + wid * 16) * 64;
    bf16x8 aq0 = *(const bf16x8*)(Q + l15 * 64 + 8 * l4);
    bf16x8 aq1 = *(const bf16x8*)(Q + l15 * 64 + 32 + 8 * l4);

    f32x4 o[4];
#pragma unroll
    for (int f = 0; f < 4; f++) o[f] = zero;
    float m_run = -1e30f;
    float l_run = 0.f;

    int kswz = (16 * g) ^ ((sr & 7) << 4);
    char* Pw = Pb + wid * 2048;
    int prow = l15 * 128;
    int pkey = (l15 & 7) << 4;
    int qloc = wid * 16 + l15;

    const u16* Kbase = kbuf + (size_t)bh * 2048 * 64;      // [s][64]
    const u16* Vbase = vbuf + (size_t)bh * 64 * 2048;      // [d][s]

    bf16x8 ck0 = *(const bf16x8*)(Kbase + (size_t)sr * 64 + g * 8);
    bf16x8 ck1 = *(const bf16x8*)(Kbase + (size_t)(sr + 32) * 64 + g * 8);
    bf16x8 cv0 = *(const bf16x8*)(Vbase + (size_t)sr * 2048 + g * 8);
    bf16x8 cv1 = *(const bf16x8*)(Vbase + (size_t)(sr + 32) * 2048 + g * 8);

    for (int kt = 0; kt <= qt; ++kt) {
        *(bf16x8*)(Ks + sr * 128 + kswz) = ck0;
        *(bf16x8*)(Ks + (sr + 32) * 128 + kswz) = ck1;
        *(bf16x8*)(Vt + sr * 128 + kswz) = cv0;
        *(bf16x8*)(Vt + (sr + 32) * 128 + kswz) = cv1;
        {
            int nkt = (kt < qt) ? kt + 1 : qt;   // clamped -> always initialized
            const u16* Kn = Kbase + (size_t)nkt * 64 * 64;
            const u16* Vn = Vbase + (size_t)nkt * 64;
            bf16x8 a = *(const bf16x8*)(Kn + (size_t)sr * 64 + g * 8);
            bf16x8 b = *(const bf16x8*)(Kn + (size_t)(sr + 32) * 64 + g * 8);
            bf16x8 c = *(const bf16x8*)(Vn + (size_t)sr * 2048 + g * 8);
            bf16x8 d = *(const bf16x8*)(Vn + (size_t)(sr + 32) * 2048 + g * 8);
            __syncthreads();

            // ---- scores (swapped): sc[nf][r] = S[ka=nf*16+4*l4+r][q=l15]
            f32x4 sc[4];
            __builtin_amdgcn_s_setprio(1);
#pragma unroll
            for (int nf = 0; nf < 4; ++nf) {
                int krow = nf * 16 + l15;
                int kkey = (krow & 7) << 4;
                bf16x8 kb0 = *(const bf16x8*)(Ks + krow * 128 + ((16 * l4) ^ kkey));
                bf16x8 kb1 = *(const bf16x8*)(Ks + krow * 128 + ((64 + 16 * l4) ^ kkey));
                f32x4 z = zero;
                z = __builtin_amdgcn_mfma_f32_16x16x32_bf16(kb0, aq0, z, 0, 0, 0);
                z = __builtin_amdgcn_mfma_f32_16x16x32_bf16(kb1, aq1, z, 0, 0, 0);
                sc[nf] = z;
            }
            __builtin_amdgcn_s_setprio(0);

            if (kt == qt) {
#pragma unroll
                for (int nf = 0; nf < 4; nf++)
#pragma unroll
                    for (int r = 0; r < 4; r++) {
                        int ka = nf * 16 + 4 * l4 + r;
                        if (ka > qloc) sc[nf][r] = -1e30f;
                    }
            }
            // ---- local max + deferred global max
            float lmax = sc[0][0];
#pragma unroll
            for (int nf = 0; nf < 4; nf++)
#pragma unroll
                for (int r = 0; r < 4; r++) lmax = fmaxf(lmax, sc[nf][r]);
            if (__any(lmax > m_run + 10.f)) {
                float m0 = lmax;
                m0 = fmaxf(m0, __shfl_xor(m0, 16));
                m0 = fmaxf(m0, __shfl_xor(m0, 32));
                float mn = fmaxf(m_run, m0);
                float al = exp2_fast(m_run - mn);
                l_run *= al;
                m_run = mn;
                float a0 = __shfl(al, 4 * l4 + 0);
                float a1 = __shfl(al, 4 * l4 + 1);
                float a2 = __shfl(al, 4 * l4 + 2);
                float a3 = __shfl(al, 4 * l4 + 3);
#pragma unroll
                for (int f = 0; f < 4; f++) {
                    o[f][0] *= a0; o[f][1] *= a1; o[f][2] *= a2; o[f][3] *= a3;
                }
            }
            // ---- exp2 + per-lane partial sum
            float psum = 0.f;
#pragma unroll
            for (int nf = 0; nf < 4; nf++)
#pragma unroll
                for (int r = 0; r < 4; r++) {
                    float pv = exp2_fast(sc[nf][r] - m_run);
                    sc[nf][r] = pv; psum += pv;
                }
            l_run += psum;
            // ---- P pack + write (k-consecutive quad per lane)
#pragma unroll
            for (int nf = 0; nf < 4; nf++) {
                uint2 w;
                w.x = cvtpk_bf16(sc[nf][0], sc[nf][1]);
                w.y = cvtpk_bf16(sc[nf][2], sc[nf][3]);
                *(uint2*)(Pw + prow + ((nf * 32 + l4 * 8) ^ pkey)) = w;
            }
            // ---- P @ V
            __builtin_amdgcn_s_setprio(1);
#pragma unroll
            for (int kk = 0; kk < 2; kk++) {
                bf16x8 pa = *(const bf16x8*)(Pw + prow + ((64 * kk + 16 * l4) ^ pkey));
#pragma unroll
                for (int f = 0; f < 4; f++) {
                    int vrow = f * 16 + l15;
                    int vkey = (vrow & 7) << 4;
                    bf16x8 vb = *(const bf16x8*)(Vt + vrow * 128 + ((64 * kk + 16 * l4) ^ vkey));
                    o[f] = __builtin_amdgcn_mfma_f32_16x16x32_bf16(pa, vb, o[f], 0, 0, 0);
                }
            }
            __builtin_amdgcn_s_setprio(0);
            __syncthreads();
            ck0 = a; ck1 = b; cv0 = c; cv1 = d;
        }
    }
    // ---- final row-sum reduce
    l_run += __shfl_xor(l_run, 16);
    l_run += __shfl_xor(l_run, 32);
#pragma unroll
    for (int r = 0; r < 4; r++) {
        float lr = __shfl(l_run, 4 * l4 + r);
        float inv = 1.f / lr;
        int qa = q0 + wid * 16 + l4 * 4 + r;
        u16* dst = ctx + (size_t)(bb * 2048 + qa) * 1024 + hh * 64;
#pragma unroll
        for (int f = 0; f < 4; f++) dst[f * 16 + l15] = f2bf(o[f][r] * inv);
    }
}

// ----------------------------------------------------------------
extern "C" void kernel_launch(void* const* d_in, const int* in_sizes, int n_in,
                              void* d_out, int out_size, void* d_ws, size_t ws_size,
                              hipStream_t stream)
{
    const float* x    = (const float*)d_in[0];
    const float* ln_g = (const float*)d_in[1];
    const float* ln_b = (const float*)d_in[2];
    const float* wqkv = (const float*)d_in[3];
    const float* bqkv = (const float*)d_in[4];
    const float* wo   = (const float*)d_in[5];
    const float* bo   = (const float*)d_in[6];
    float* out = (float*)d_out;

    char* ws = (char*)d_ws;
    u16* hbuf  = (u16*)ws;                          // 8 MB   LN out
    u16* qkvb  = (u16*)(ws + 8388608);              // 24 MB  q/k head-major, v transposed
    u16* ctxb  = (u16*)(ws + 33554432);             // 8 MB   (wqkvT first, then ctx)
    u16* wqkvT = ctxb;                              // 6.29 MB (dead before attn writes ctx)
    u16* woT   = (u16*)(ws + 41943040);             // 2 MB   @40MB (hbuf is still live in prep)

    prep_kernel<<<5120, 256, 0, stream>>>(x, ln_g, ln_b, hbuf, wqkv, wqkvT, wo, woT);
    qkv_gemm128<<<dim3(24, 32), 256, 0, stream>>>(hbuf, wqkvT, bqkv, qkvb);
    attn_kernel<<<1024, 256, 0, stream>>>(
        qkvb, qkvb + QKV_SZ, qkvb + 2 * QKV_SZ, ctxb);
    out_gemm128<<<dim3(16, 32), 256, 0, stream>>>(ctxb, woT, bo, x, out);
}